// Round 2
// baseline (872.423 us; speedup 1.0000x reference)
//
#include <hip/hip_runtime.h>
#include <hip/hip_bf16.h>
#include <cstdint>
#include <cstddef>

// Problem constants (B=1)
#define EN 400000   // edges
#define NN 25000    // nodes
// D=128, H=4, DK=DV=32

typedef __attribute__((ext_vector_type(8))) short bf16x8;
typedef __attribute__((ext_vector_type(4))) short bf16x4;
typedef __attribute__((ext_vector_type(4))) float f32x4;

__device__ __forceinline__ short f2bf(float f) {
    unsigned int u = __float_as_uint(f);
    u = (u + 0x7fffu + ((u >> 16) & 1u)) >> 16;   // RNE
    return (short)u;
}
__device__ __forceinline__ float bf2f(short s) {
    return __uint_as_float(((unsigned int)(unsigned short)s) << 16);
}

// ---------------- K0: weights -> bf16 hi (5 mats) + bf16 lo (WQ,WK,WE) ----------------
__global__ __launch_bounds__(256) void convert_w_kernel(
    const float* __restrict__ w0, const float* __restrict__ w1,
    const float* __restrict__ w2, const float* __restrict__ w3,
    const float* __restrict__ w4, short* __restrict__ hi, short* __restrict__ lo)
{
    int i = blockIdx.x * 256 + threadIdx.x;      // 131072 threads total
    if (i < 81920) {
        int w = i >> 14, off = i & 16383;
        const float* src = (w == 0) ? w0 : (w == 1) ? w1 : (w == 2) ? w2 : (w == 3) ? w3 : w4;
        hi[i] = f2bf(src[off]);
    } else {
        int j = i - 81920;                       // 0..49151: WQ, WK, WE lo parts
        int m = j >> 14, off = j & 16383;
        const float* src = (m == 0) ? w0 : (m == 1) ? w1 : w3;
        float x = src[off];
        short h = f2bf(x);
        lo[j] = f2bf(x - bf2f(h));
    }
}

// ---------------- K1a: split-precision projection, fp32 output (Q, K) ----------------
// Per wave: 16 rows. 3-pass hi/lo MFMA: err ~2^-17 (fp32-class).
__global__ __launch_bounds__(256) void proj_split_kernel(
    const float* __restrict__ X, const short* __restrict__ Whi,
    const short* __restrict__ Wlo, float* __restrict__ P, int nrows)
{
    const int lane = threadIdx.x & 63;
    const int wave = threadIdx.x >> 6;
    const int el = lane & 15;
    const int g  = lane >> 4;
    const int row = blockIdx.x * 64 + wave * 16 + el;
    const int rc  = row < nrows ? row : nrows - 1;

    f32x4 acc[8] = {};
    const float* xrow = X + (size_t)rc * 128;
#pragma unroll
    for (int kc = 0; kc < 4; ++kc) {
        const int kb = kc * 32 + g * 8;
        f32x4 x0 = *(const f32x4*)(xrow + kb);
        f32x4 x1 = *(const f32x4*)(xrow + kb + 4);
        bf16x8 bh, bl;
#pragma unroll
        for (int j = 0; j < 4; ++j) {
            bh[j] = f2bf(x0[j]); bl[j] = f2bf(x0[j] - bf2f(bh[j]));
            bh[4 + j] = f2bf(x1[j]); bl[4 + j] = f2bf(x1[j] - bf2f(bh[4 + j]));
        }
#pragma unroll
        for (int dt = 0; dt < 8; ++dt) {
            bf16x8 ah = *(const bf16x8*)(Whi + (dt * 16 + el) * 128 + kb);
            bf16x8 al = *(const bf16x8*)(Wlo + (dt * 16 + el) * 128 + kb);
            acc[dt] = __builtin_amdgcn_mfma_f32_16x16x32_bf16(ah, bh, acc[dt], 0, 0, 0);
            acc[dt] = __builtin_amdgcn_mfma_f32_16x16x32_bf16(ah, bl, acc[dt], 0, 0, 0);
            acc[dt] = __builtin_amdgcn_mfma_f32_16x16x32_bf16(al, bh, acc[dt], 0, 0, 0);
        }
    }
    if (row < nrows) {
#pragma unroll
        for (int dt = 0; dt < 8; ++dt)
            *(f32x4*)(P + (size_t)row * 128 + dt * 16 + g * 4) = acc[dt];
    }
}

// ---------------- K1b: single-pass bf16 projection (V) ----------------
__global__ __launch_bounds__(256) void proj_kernel(
    const float* __restrict__ X, const short* __restrict__ Wb,
    short* __restrict__ P, int nrows)
{
    const int lane = threadIdx.x & 63;
    const int wave = threadIdx.x >> 6;
    const int el = lane & 15;
    const int g  = lane >> 4;
    const int row = blockIdx.x * 64 + wave * 16 + el;
    const int rc  = row < nrows ? row : nrows - 1;

    f32x4 acc[8] = {};
    const float* xrow = X + (size_t)rc * 128;
#pragma unroll
    for (int kc = 0; kc < 4; ++kc) {
        const int kb = kc * 32 + g * 8;
        f32x4 x0 = *(const f32x4*)(xrow + kb);
        f32x4 x1 = *(const f32x4*)(xrow + kb + 4);
        bf16x8 b;
        b[0] = f2bf(x0[0]); b[1] = f2bf(x0[1]); b[2] = f2bf(x0[2]); b[3] = f2bf(x0[3]);
        b[4] = f2bf(x1[0]); b[5] = f2bf(x1[1]); b[6] = f2bf(x1[2]); b[7] = f2bf(x1[3]);
#pragma unroll
        for (int dt = 0; dt < 8; ++dt) {
            bf16x8 a = *(const bf16x8*)(Wb + (dt * 16 + el) * 128 + kb);
            acc[dt] = __builtin_amdgcn_mfma_f32_16x16x32_bf16(a, b, acc[dt], 0, 0, 0);
        }
    }
    if (row < nrows) {
#pragma unroll
        for (int dt = 0; dt < 8; ++dt) {
            bf16x4 o;
#pragma unroll
            for (int j = 0; j < 4; ++j) o[j] = f2bf(acc[dt][j]);
            *(bf16x4*)(P + (size_t)row * 128 + dt * 16 + g * 4) = o;
        }
    }
}

// ---------------- K2: fused split-precision Ef-GEMM + edge attention + scatter --------
// Per wave: 16 edges. Lane owns edge e=lane&15, dims d = dt*16+(lane>>4)*4+j.
__global__ __launch_bounds__(256) void edge_kernel(
    const int* __restrict__ eidx, const float* __restrict__ efeat,
    const float* __restrict__ Qf, const float* __restrict__ Kf,
    const short* __restrict__ Vb, const short* __restrict__ WEhi,
    const short* __restrict__ WElo,
    float* __restrict__ accum, float* __restrict__ coeff,
    float* __restrict__ attn_out)
{
    const int lane = threadIdx.x & 63;
    const int wave = threadIdx.x >> 6;
    const int el = lane & 15;
    const int g  = lane >> 4;
    const int edge = blockIdx.x * 64 + wave * 16 + el;   // 6250*64 = 400000 exactly

    f32x4 acc[8] = {};
    const float* efrow = efeat + (size_t)edge * 128;
#pragma unroll
    for (int kc = 0; kc < 4; ++kc) {
        const int kb = kc * 32 + g * 8;
        f32x4 x0 = *(const f32x4*)(efrow + kb);
        f32x4 x1 = *(const f32x4*)(efrow + kb + 4);
        bf16x8 bh, bl;
#pragma unroll
        for (int j = 0; j < 4; ++j) {
            bh[j] = f2bf(x0[j]); bl[j] = f2bf(x0[j] - bf2f(bh[j]));
            bh[4 + j] = f2bf(x1[j]); bl[4 + j] = f2bf(x1[j] - bf2f(bh[4 + j]));
        }
#pragma unroll
        for (int dt = 0; dt < 8; ++dt) {
            bf16x8 ah = *(const bf16x8*)(WEhi + (dt * 16 + el) * 128 + kb);
            bf16x8 al = *(const bf16x8*)(WElo + (dt * 16 + el) * 128 + kb);
            acc[dt] = __builtin_amdgcn_mfma_f32_16x16x32_bf16(ah, bh, acc[dt], 0, 0, 0);
            acc[dt] = __builtin_amdgcn_mfma_f32_16x16x32_bf16(ah, bl, acc[dt], 0, 0, 0);
            acc[dt] = __builtin_amdgcn_mfma_f32_16x16x32_bf16(al, bh, acc[dt], 0, 0, 0);
        }
    }

    const int src = eidx[edge];
    const int tgt = eidx[EN + edge];
    const size_t qoff = (size_t)src * 128;
    const size_t koff = (size_t)tgt * 128;

    float part[4] = {0.f, 0.f, 0.f, 0.f};
    float vv[8][4];
#pragma unroll
    for (int dt = 0; dt < 8; ++dt) {
        const int dbase = dt * 16 + g * 4;
        f32x4 q4 = *(const f32x4*)(Qf + qoff + dbase);
        f32x4 k4 = *(const f32x4*)(Kf + koff + dbase);
        bf16x4 v4 = *(const bf16x4*)(Vb + koff + dbase);
        const int h = dt >> 1;
#pragma unroll
        for (int j = 0; j < 4; ++j) {
            part[h] += q4[j] * k4[j] * acc[dt][j];
            vv[dt][j] = bf2f(v4[j]);
        }
    }

    float attn[4];
#pragma unroll
    for (int h = 0; h < 4; ++h) {
        float t = part[h];
        t += __shfl_xor(t, 16, 64);
        t += __shfl_xor(t, 32, 64);           // all 4 g-lanes now hold full 32-sum
        t *= 0.17677669529663687f;            // 1/sqrt(32)
        t = fminf(5.0f, fmaxf(-5.0f, t));
        attn[h] = expf(t);
    }

    attn_out[(size_t)g * EN + edge] = attn[g];            // head g, coalesced per 16-lane group
    unsafeAtomicAdd(coeff + src * 4 + g, attn[g]);        // exactly one per (edge, head)

    float* arow = accum + qoff;
#pragma unroll
    for (int dt = 0; dt < 8; ++dt) {
        const int dbase = dt * 16 + g * 4;
        const float ah = attn[dt >> 1];
#pragma unroll
        for (int j = 0; j < 4; ++j)
            unsafeAtomicAdd(arow + dbase + j, ah * vv[dt][j]);
    }
}

// ---------------- K3: normalize + W_fc matvec + residual + LayerNorm ----------------
// Block: 256 threads = 16 nodes. Thread (n_l=t>>4, c=t&15) computes dims d = c + 16*i.
__global__ __launch_bounds__(256) void final_kernel(
    const float* __restrict__ accum, const float* __restrict__ coeff,
    const short* __restrict__ Wfcb, const float* __restrict__ inQ,
    const float* __restrict__ gamma, const float* __restrict__ beta,
    float* __restrict__ y)
{
    __shared__ short wlds[128 * 136];   // padded: stride 136 bf16 -> 2-way banks
    __shared__ float alds[16 * 132];    // padded: stride 132 f32

    const int t = threadIdx.x;
    // stage W_fc (bf16): thread handles row r=t>>1, cols (t&1)*64..+63
    {
        const int r = t >> 1, colb = (t & 1) * 64;
#pragma unroll
        for (int c = 0; c < 8; ++c) {
            bf16x8 w = *(const bf16x8*)(Wfcb + r * 128 + colb + c * 8);
            *(bf16x8*)(&wlds[r * 136 + colb + c * 8]) = w;
        }
    }

    const int n_l = t >> 4;
    const int c16 = t & 15;
    const int node = blockIdx.x * 16 + n_l;
    const int kk = c16 * 8;             // 8 elems, all within head kk>>5
    {
        float av[8];
        if (node < NN) {
            f32x4 a0 = *(const f32x4*)(accum + (size_t)node * 128 + kk);
            f32x4 a1 = *(const f32x4*)(accum + (size_t)node * 128 + kk + 4);
            const float inv = 1.0f / (coeff[node * 4 + (kk >> 5)] + 1e-8f);
            av[0] = a0[0] * inv; av[1] = a0[1] * inv; av[2] = a0[2] * inv; av[3] = a0[3] * inv;
            av[4] = a1[0] * inv; av[5] = a1[1] * inv; av[6] = a1[2] * inv; av[7] = a1[3] * inv;
        } else {
#pragma unroll
            for (int j = 0; j < 8; ++j) av[j] = 0.f;
        }
#pragma unroll
        for (int j = 0; j < 8; ++j) alds[n_l * 132 + kk + j] = av[j];
    }
    __syncthreads();

    float fc[8] = {};
#pragma unroll 4
    for (int k0 = 0; k0 < 128; k0 += 8) {
        float a8[8];
#pragma unroll
        for (int j = 0; j < 8; ++j) a8[j] = alds[n_l * 132 + k0 + j];
#pragma unroll
        for (int i = 0; i < 8; ++i) {
            const int d = c16 + 16 * i;
            bf16x8 w = *(const bf16x8*)(&wlds[d * 136 + k0]);
#pragma unroll
            for (int j = 0; j < 8; ++j) fc[i] += a8[j] * bf2f(w[j]);
        }
    }

    if (node < NN) {
        float x[8];
        float s = 0.f, s2 = 0.f;
#pragma unroll
        for (int i = 0; i < 8; ++i) {
            const int d = c16 + 16 * i;
            x[i] = fc[i] + inQ[(size_t)node * 128 + d];
            s += x[i]; s2 += x[i] * x[i];
        }
        // reduce across the 16 threads of this node (lanes differ in low 4 bits)
        s  += __shfl_xor(s, 1, 64);  s2 += __shfl_xor(s2, 1, 64);
        s  += __shfl_xor(s, 2, 64);  s2 += __shfl_xor(s2, 2, 64);
        s  += __shfl_xor(s, 4, 64);  s2 += __shfl_xor(s2, 4, 64);
        s  += __shfl_xor(s, 8, 64);  s2 += __shfl_xor(s2, 8, 64);
        const float mu = s * (1.0f / 128.0f);
        const float var = s2 * (1.0f / 128.0f) - mu * mu;
        const float rstd = rsqrtf(var + 1e-5f);
#pragma unroll
        for (int i = 0; i < 8; ++i) {
            const int d = c16 + 16 * i;
            y[(size_t)node * 128 + d] = (x[i] - mu) * rstd * gamma[d] + beta[d];
        }
    }
}

// ---------------- launcher ----------------
extern "C" void kernel_launch(void* const* d_in, const int* in_sizes, int n_in,
                              void* d_out, int out_size, void* d_ws, size_t ws_size,
                              hipStream_t stream) {
    const int*   eidx  = (const int*)d_in[0];
    const float* efeat = (const float*)d_in[1];
    const float* inQ   = (const float*)d_in[2];
    const float* inK   = (const float*)d_in[3];
    const float* inV   = (const float*)d_in[4];
    const float* WQ    = (const float*)d_in[5];
    const float* WK    = (const float*)d_in[6];
    const float* WV    = (const float*)d_in[7];
    const float* WE    = (const float*)d_in[8];
    const float* Wfc   = (const float*)d_in[9];
    const float* gamma = (const float*)d_in[10];
    const float* beta  = (const float*)d_in[11];

    float* y = (float*)d_out;
    float* attn_out = y + (size_t)NN * 128;   // 3,200,000

    // ws layout (bytes):
    //   Qf f32 (25000x128):   12,800,000   @ 0
    //   Kf f32:               12,800,000   @ 12,800,000
    //   Vb bf16:               6,400,000   @ 25,600,000
    //   Whi (5x16384 bf16):      163,840   @ 32,000,000
    //   Wlo (3x16384 bf16):       98,304   @ 32,163,840
    //   accum f32:            12,800,000   @ 32,262,144
    //   coeff f32:               400,000   @ 45,062,144  -> total 45,462,144
    char* ws = (char*)d_ws;
    float* Qf = (float*)ws;
    float* Kf = (float*)(ws + 12800000);
    short* Vb = (short*)(ws + 25600000);
    short* Whi = (short*)(ws + 32000000);
    short* Wlo = (short*)(ws + 32163840);
    float* accum = (float*)(ws + 32262144);
    float* coeff = (float*)(ws + 45062144);

    hipMemsetAsync(accum, 0, (size_t)NN * 128 * 4 + (size_t)NN * 4 * 4, stream);

    convert_w_kernel<<<512, 256, 0, stream>>>(WQ, WK, WV, WE, Wfc, Whi, Wlo);

    proj_split_kernel<<<391, 256, 0, stream>>>(inQ, Whi,         Wlo,         Qf, NN);
    proj_split_kernel<<<391, 256, 0, stream>>>(inK, Whi + 16384, Wlo + 16384, Kf, NN);
    proj_kernel<<<391, 256, 0, stream>>>(inV, Whi + 2 * 16384, Vb, NN);

    edge_kernel<<<EN / 64, 256, 0, stream>>>(eidx, efeat, Qf, Kf, Vb,
                                             Whi + 3 * 16384, Wlo + 2 * 16384,
                                             accum, coeff, attn_out);

    final_kernel<<<(NN + 15) / 16, 256, 0, stream>>>(accum, coeff, Whi + 4 * 16384,
                                                     inQ, gamma, beta, y);
}

// Round 3
// 462.039 us; speedup vs baseline: 1.8882x; 1.8882x over previous
//
#include <hip/hip_runtime.h>
#include <hip/hip_bf16.h>
#include <cstdint>
#include <cstddef>

// Problem constants (B=1)
#define EN 400000   // edges
#define NN 25000    // nodes
// D=128, H=4, DK=DV=32

typedef __attribute__((ext_vector_type(8))) short bf16x8;
typedef __attribute__((ext_vector_type(4))) short bf16x4;
typedef __attribute__((ext_vector_type(4))) float f32x4;

__device__ __forceinline__ short f2bf(float f) {
    unsigned int u = __float_as_uint(f);
    u = (u + 0x7fffu + ((u >> 16) & 1u)) >> 16;   // RNE
    return (short)u;
}
__device__ __forceinline__ float bf2f(short s) {
    return __uint_as_float(((unsigned int)(unsigned short)s) << 16);
}

// ---------------- K0: weights -> bf16 hi (5 mats) + bf16 lo (WQ,WK,WE) ----------------
__global__ __launch_bounds__(256) void convert_w_kernel(
    const float* __restrict__ w0, const float* __restrict__ w1,
    const float* __restrict__ w2, const float* __restrict__ w3,
    const float* __restrict__ w4, short* __restrict__ hi, short* __restrict__ lo)
{
    int i = blockIdx.x * 256 + threadIdx.x;      // 131072 threads total
    if (i < 81920) {
        int w = i >> 14, off = i & 16383;
        const float* src = (w == 0) ? w0 : (w == 1) ? w1 : (w == 2) ? w2 : (w == 3) ? w3 : w4;
        hi[i] = f2bf(src[off]);
    } else {
        int j = i - 81920;                       // 0..49151: WQ, WK, WE lo parts
        int m = j >> 14, off = j & 16383;
        const float* src = (m == 0) ? w0 : (m == 1) ? w1 : w3;
        float x = src[off];
        short h = f2bf(x);
        lo[j] = f2bf(x - bf2f(h));
    }
}

// ---------------- CSR build ----------------
__global__ __launch_bounds__(256) void hist_kernel(
    const int* __restrict__ eidx, int* __restrict__ deg)
{
    int e = blockIdx.x * 256 + threadIdx.x;
    if (e < EN) atomicAdd(&deg[eidx[e]], 1);
}

__global__ __launch_bounds__(1024) void scan_kernel(
    const int* __restrict__ deg, int* __restrict__ base)
{
    __shared__ int part[1024];
    const int t = threadIdx.x;
    const int CH = 25;                       // 1024*25 = 25600 >= NN
    int loc[CH];
    int s = 0;
#pragma unroll
    for (int i = 0; i < CH; ++i) {
        int idx = t * CH + i;
        loc[i] = s;
        s += (idx < NN) ? deg[idx] : 0;
    }
    part[t] = s;
    __syncthreads();
    for (int d = 1; d < 1024; d <<= 1) {
        int v = (t >= d) ? part[t - d] : 0;
        __syncthreads();
        part[t] += v;
        __syncthreads();
    }
    int off = (t > 0) ? part[t - 1] : 0;
#pragma unroll
    for (int i = 0; i < CH; ++i) {
        int idx = t * CH + i;
        if (idx < NN) base[idx] = off + loc[i];
    }
    if (t == 1023) base[NN] = part[1023];
}

__global__ __launch_bounds__(256) void scatter_kernel(
    const int* __restrict__ eidx, const int* __restrict__ base,
    int* __restrict__ cnt, int* __restrict__ csr)
{
    int e = blockIdx.x * 256 + threadIdx.x;
    if (e < EN) {
        int s = eidx[e];
        int p = base[s] + atomicAdd(&cnt[s], 1);
        csr[p] = e;
    }
}

// ---------------- K1a: split-precision projection, fp32 output (Q, K) ----------------
__global__ __launch_bounds__(256) void proj_split_kernel(
    const float* __restrict__ X, const short* __restrict__ Whi,
    const short* __restrict__ Wlo, float* __restrict__ P, int nrows)
{
    const int lane = threadIdx.x & 63;
    const int wave = threadIdx.x >> 6;
    const int el = lane & 15;
    const int g  = lane >> 4;
    const int row = blockIdx.x * 64 + wave * 16 + el;
    const int rc  = row < nrows ? row : nrows - 1;

    f32x4 acc[8] = {};
    const float* xrow = X + (size_t)rc * 128;
#pragma unroll
    for (int kc = 0; kc < 4; ++kc) {
        const int kb = kc * 32 + g * 8;
        f32x4 x0 = *(const f32x4*)(xrow + kb);
        f32x4 x1 = *(const f32x4*)(xrow + kb + 4);
        bf16x8 bh, bl;
#pragma unroll
        for (int j = 0; j < 4; ++j) {
            bh[j] = f2bf(x0[j]); bl[j] = f2bf(x0[j] - bf2f(bh[j]));
            bh[4 + j] = f2bf(x1[j]); bl[4 + j] = f2bf(x1[j] - bf2f(bh[4 + j]));
        }
#pragma unroll
        for (int dt = 0; dt < 8; ++dt) {
            bf16x8 ah = *(const bf16x8*)(Whi + (dt * 16 + el) * 128 + kb);
            bf16x8 al = *(const bf16x8*)(Wlo + (dt * 16 + el) * 128 + kb);
            acc[dt] = __builtin_amdgcn_mfma_f32_16x16x32_bf16(ah, bh, acc[dt], 0, 0, 0);
            acc[dt] = __builtin_amdgcn_mfma_f32_16x16x32_bf16(ah, bl, acc[dt], 0, 0, 0);
            acc[dt] = __builtin_amdgcn_mfma_f32_16x16x32_bf16(al, bh, acc[dt], 0, 0, 0);
        }
    }
    if (row < nrows) {
#pragma unroll
        for (int dt = 0; dt < 8; ++dt)
            *(f32x4*)(P + (size_t)row * 128 + dt * 16 + g * 4) = acc[dt];
    }
}

// ---------------- K1b: single-pass bf16 projection (V) ----------------
__global__ __launch_bounds__(256) void proj_kernel(
    const float* __restrict__ X, const short* __restrict__ Wb,
    short* __restrict__ P, int nrows)
{
    const int lane = threadIdx.x & 63;
    const int wave = threadIdx.x >> 6;
    const int el = lane & 15;
    const int g  = lane >> 4;
    const int row = blockIdx.x * 64 + wave * 16 + el;
    const int rc  = row < nrows ? row : nrows - 1;

    f32x4 acc[8] = {};
    const float* xrow = X + (size_t)rc * 128;
#pragma unroll
    for (int kc = 0; kc < 4; ++kc) {
        const int kb = kc * 32 + g * 8;
        f32x4 x0 = *(const f32x4*)(xrow + kb);
        f32x4 x1 = *(const f32x4*)(xrow + kb + 4);
        bf16x8 b;
        b[0] = f2bf(x0[0]); b[1] = f2bf(x0[1]); b[2] = f2bf(x0[2]); b[3] = f2bf(x0[3]);
        b[4] = f2bf(x1[0]); b[5] = f2bf(x1[1]); b[6] = f2bf(x1[2]); b[7] = f2bf(x1[3]);
#pragma unroll
        for (int dt = 0; dt < 8; ++dt) {
            bf16x8 a = *(const bf16x8*)(Wb + (dt * 16 + el) * 128 + kb);
            acc[dt] = __builtin_amdgcn_mfma_f32_16x16x32_bf16(a, b, acc[dt], 0, 0, 0);
        }
    }
    if (row < nrows) {
#pragma unroll
        for (int dt = 0; dt < 8; ++dt) {
            bf16x4 o;
#pragma unroll
            for (int j = 0; j < 4; ++j) o[j] = f2bf(acc[dt][j]);
            *(bf16x4*)(P + (size_t)row * 128 + dt * 16 + g * 4) = o;
        }
    }
}

// ---------------- K2: CSR-ordered edge kernel + segmented in-wave reduce ----------------
// Per wave: 16 CSR positions. Lane owns edge e=csr[pos(el)], dims d = dt*16+g*4+j.
__global__ __launch_bounds__(256) void edge_kernel(
    const int* __restrict__ eidx, const int* __restrict__ csr,
    const float* __restrict__ efeat,
    const float* __restrict__ Qf, const float* __restrict__ Kf,
    const short* __restrict__ Vb, const short* __restrict__ WEhi,
    const short* __restrict__ WElo,
    float* __restrict__ accum, float* __restrict__ coeff,
    float* __restrict__ attn_out)
{
    const int lane = threadIdx.x & 63;
    const int wave = threadIdx.x >> 6;
    const int el = lane & 15;
    const int g  = lane >> 4;
    const int pos = blockIdx.x * 64 + wave * 16 + el;    // 6250*64 = 400000 exactly
    const int edge = csr[pos];

    f32x4 acc[8] = {};
    const float* efrow = efeat + (size_t)edge * 128;
#pragma unroll
    for (int kc = 0; kc < 4; ++kc) {
        const int kb = kc * 32 + g * 8;
        f32x4 x0 = *(const f32x4*)(efrow + kb);
        f32x4 x1 = *(const f32x4*)(efrow + kb + 4);
        bf16x8 bh, bl;
#pragma unroll
        for (int j = 0; j < 4; ++j) {
            bh[j] = f2bf(x0[j]); bl[j] = f2bf(x0[j] - bf2f(bh[j]));
            bh[4 + j] = f2bf(x1[j]); bl[4 + j] = f2bf(x1[j] - bf2f(bh[4 + j]));
        }
#pragma unroll
        for (int dt = 0; dt < 8; ++dt) {
            bf16x8 ah = *(const bf16x8*)(WEhi + (dt * 16 + el) * 128 + kb);
            bf16x8 al = *(const bf16x8*)(WElo + (dt * 16 + el) * 128 + kb);
            acc[dt] = __builtin_amdgcn_mfma_f32_16x16x32_bf16(ah, bh, acc[dt], 0, 0, 0);
            acc[dt] = __builtin_amdgcn_mfma_f32_16x16x32_bf16(ah, bl, acc[dt], 0, 0, 0);
            acc[dt] = __builtin_amdgcn_mfma_f32_16x16x32_bf16(al, bh, acc[dt], 0, 0, 0);
        }
    }

    const int src = eidx[edge];
    const int tgt = eidx[EN + edge];
    const size_t qoff = (size_t)src * 128;
    const size_t koff = (size_t)tgt * 128;

    float part[4] = {0.f, 0.f, 0.f, 0.f};
    float vv[8][4];
#pragma unroll
    for (int dt = 0; dt < 8; ++dt) {
        const int dbase = dt * 16 + g * 4;
        f32x4 q4 = *(const f32x4*)(Qf + qoff + dbase);
        f32x4 k4 = *(const f32x4*)(Kf + koff + dbase);
        bf16x4 v4 = *(const bf16x4*)(Vb + koff + dbase);
        const int h = dt >> 1;
#pragma unroll
        for (int j = 0; j < 4; ++j) {
            part[h] += q4[j] * k4[j] * acc[dt][j];
            vv[dt][j] = bf2f(v4[j]);
        }
    }

    float attn[4];
#pragma unroll
    for (int h = 0; h < 4; ++h) {
        float t = part[h];
        t += __shfl_xor(t, 16, 64);
        t += __shfl_xor(t, 32, 64);           // all 4 g-lanes now hold full 32-sum
        t *= 0.17677669529663687f;            // 1/sqrt(32)
        t = fminf(5.0f, fmaxf(-5.0f, t));
        attn[h] = expf(t);
    }

    attn_out[(size_t)g * EN + edge] = attn[g];   // scattered 4B write per (edge, head)

    // per-edge message (attn-weighted V), then segmented inclusive scan over el
    float msg[8][4];
#pragma unroll
    for (int dt = 0; dt < 8; ++dt) {
        const float ah = attn[dt >> 1];
#pragma unroll
        for (int j = 0; j < 4; ++j) msg[dt][j] = ah * vv[dt][j];
    }
    float cval = attn[g];

#pragma unroll
    for (int d = 1; d < 16; d <<= 1) {
        int so = __shfl_up(src, d, 16);
        const bool same = (el >= d) && (so == src);
#pragma unroll
        for (int dt = 0; dt < 8; ++dt)
#pragma unroll
            for (int j = 0; j < 4; ++j) {
                float o = __shfl_up(msg[dt][j], d, 16);
                msg[dt][j] += same ? o : 0.f;
            }
        float oc = __shfl_up(cval, d, 16);
        cval += same ? oc : 0.f;
    }

    const int nsrc = __shfl_down(src, 1, 16);
    const bool lastlane = (el == 15) || (nsrc != src);
    if (lastlane) {
        unsafeAtomicAdd(coeff + src * 4 + g, cval);
        float* arow = accum + qoff;
#pragma unroll
        for (int dt = 0; dt < 8; ++dt) {
            const int dbase = dt * 16 + g * 4;
#pragma unroll
            for (int j = 0; j < 4; ++j)
                unsafeAtomicAdd(arow + dbase + j, msg[dt][j]);
        }
    }
}

// ---------------- K3: normalize + W_fc matvec + residual + LayerNorm ----------------
__global__ __launch_bounds__(256) void final_kernel(
    const float* __restrict__ accum, const float* __restrict__ coeff,
    const short* __restrict__ Wfcb, const float* __restrict__ inQ,
    const float* __restrict__ gamma, const float* __restrict__ beta,
    float* __restrict__ y)
{
    __shared__ short wlds[128 * 136];   // padded: stride 136 bf16 -> 2-way banks
    __shared__ float alds[16 * 132];    // padded: stride 132 f32

    const int t = threadIdx.x;
    {
        const int r = t >> 1, colb = (t & 1) * 64;
#pragma unroll
        for (int c = 0; c < 8; ++c) {
            bf16x8 w = *(const bf16x8*)(Wfcb + r * 128 + colb + c * 8);
            *(bf16x8*)(&wlds[r * 136 + colb + c * 8]) = w;
        }
    }

    const int n_l = t >> 4;
    const int c16 = t & 15;
    const int node = blockIdx.x * 16 + n_l;
    const int kk = c16 * 8;
    {
        float av[8];
        if (node < NN) {
            f32x4 a0 = *(const f32x4*)(accum + (size_t)node * 128 + kk);
            f32x4 a1 = *(const f32x4*)(accum + (size_t)node * 128 + kk + 4);
            const float inv = 1.0f / (coeff[node * 4 + (kk >> 5)] + 1e-8f);
            av[0] = a0[0] * inv; av[1] = a0[1] * inv; av[2] = a0[2] * inv; av[3] = a0[3] * inv;
            av[4] = a1[0] * inv; av[5] = a1[1] * inv; av[6] = a1[2] * inv; av[7] = a1[3] * inv;
        } else {
#pragma unroll
            for (int j = 0; j < 8; ++j) av[j] = 0.f;
        }
#pragma unroll
        for (int j = 0; j < 8; ++j) alds[n_l * 132 + kk + j] = av[j];
    }
    __syncthreads();

    float fc[8] = {};
#pragma unroll 4
    for (int k0 = 0; k0 < 128; k0 += 8) {
        float a8[8];
#pragma unroll
        for (int j = 0; j < 8; ++j) a8[j] = alds[n_l * 132 + k0 + j];
#pragma unroll
        for (int i = 0; i < 8; ++i) {
            const int d = c16 + 16 * i;
            bf16x8 w = *(const bf16x8*)(&wlds[d * 136 + k0]);
#pragma unroll
            for (int j = 0; j < 8; ++j) fc[i] += a8[j] * bf2f(w[j]);
        }
    }

    if (node < NN) {
        float x[8];
        float s = 0.f, s2 = 0.f;
#pragma unroll
        for (int i = 0; i < 8; ++i) {
            const int d = c16 + 16 * i;
            x[i] = fc[i] + inQ[(size_t)node * 128 + d];
            s += x[i]; s2 += x[i] * x[i];
        }
        s  += __shfl_xor(s, 1, 64);  s2 += __shfl_xor(s2, 1, 64);
        s  += __shfl_xor(s, 2, 64);  s2 += __shfl_xor(s2, 2, 64);
        s  += __shfl_xor(s, 4, 64);  s2 += __shfl_xor(s2, 4, 64);
        s  += __shfl_xor(s, 8, 64);  s2 += __shfl_xor(s2, 8, 64);
        const float mu = s * (1.0f / 128.0f);
        const float var = s2 * (1.0f / 128.0f) - mu * mu;
        const float rstd = rsqrtf(var + 1e-5f);
#pragma unroll
        for (int i = 0; i < 8; ++i) {
            const int d = c16 + 16 * i;
            y[(size_t)node * 128 + d] = (x[i] - mu) * rstd * gamma[d] + beta[d];
        }
    }
}

// ---------------- launcher ----------------
extern "C" void kernel_launch(void* const* d_in, const int* in_sizes, int n_in,
                              void* d_out, int out_size, void* d_ws, size_t ws_size,
                              hipStream_t stream) {
    const int*   eidx  = (const int*)d_in[0];
    const float* efeat = (const float*)d_in[1];
    const float* inQ   = (const float*)d_in[2];
    const float* inK   = (const float*)d_in[3];
    const float* inV   = (const float*)d_in[4];
    const float* WQ    = (const float*)d_in[5];
    const float* WK    = (const float*)d_in[6];
    const float* WV    = (const float*)d_in[7];
    const float* WE    = (const float*)d_in[8];
    const float* Wfc   = (const float*)d_in[9];
    const float* gamma = (const float*)d_in[10];
    const float* beta  = (const float*)d_in[11];

    float* y = (float*)d_out;
    float* attn_out = y + (size_t)NN * 128;   // 3,200,000

    // ws layout (bytes):
    //   Qf f32:            12,800,000 @ 0
    //   Kf f32:            12,800,000 @ 12,800,000
    //   Vb bf16:            6,400,000 @ 25,600,000
    //   Whi (5x16384):        163,840 @ 32,000,000
    //   Wlo (3x16384):         98,304 @ 32,163,840
    //   accum f32:         12,800,000 @ 32,262,144
    //   coeff f32:            400,000 @ 45,062,144
    //   csr int:            1,600,000 @ 45,462,144
    //   deg int:              100,352 @ 47,062,144
    //   cnt int:              100,352 @ 47,162,496
    //   base int:             100,352 @ 47,262,848  -> total 47,363,200
    char* ws = (char*)d_ws;
    float* Qf    = (float*)ws;
    float* Kf    = (float*)(ws + 12800000);
    short* Vb    = (short*)(ws + 25600000);
    short* Whi   = (short*)(ws + 32000000);
    short* Wlo   = (short*)(ws + 32163840);
    float* accum = (float*)(ws + 32262144);
    float* coeff = (float*)(ws + 45062144);
    int*   csr   = (int*)  (ws + 45462144);
    int*   deg   = (int*)  (ws + 47062144);
    int*   cnt   = (int*)  (ws + 47162496);
    int*   base  = (int*)  (ws + 47262848);

    hipMemsetAsync(accum, 0, (size_t)NN * 128 * 4 + (size_t)NN * 4 * 4, stream); // accum+coeff
    hipMemsetAsync(deg, 0, 200704, stream);                                      // deg+cnt

    // CSR build
    hist_kernel<<<(EN + 255) / 256, 256, 0, stream>>>(eidx, deg);
    scan_kernel<<<1, 1024, 0, stream>>>(deg, base);
    scatter_kernel<<<(EN + 255) / 256, 256, 0, stream>>>(eidx, base, cnt, csr);

    convert_w_kernel<<<512, 256, 0, stream>>>(WQ, WK, WV, WE, Wfc, Whi, Wlo);

    proj_split_kernel<<<391, 256, 0, stream>>>(inQ, Whi,         Wlo,         Qf, NN);
    proj_split_kernel<<<391, 256, 0, stream>>>(inK, Whi + 16384, Wlo + 16384, Kf, NN);
    proj_kernel<<<391, 256, 0, stream>>>(inV, Whi + 2 * 16384, Vb, NN);

    edge_kernel<<<EN / 64, 256, 0, stream>>>(eidx, csr, efeat, Qf, Kf, Vb,
                                             Whi + 3 * 16384, Wlo + 2 * 16384,
                                             accum, coeff, attn_out);

    final_kernel<<<(NN + 15) / 16, 256, 0, stream>>>(accum, coeff, Whi + 4 * 16384,
                                                     inQ, gamma, beta, y);
}

// Round 4
// 444.646 us; speedup vs baseline: 1.9621x; 1.0391x over previous
//
#include <hip/hip_runtime.h>
#include <hip/hip_bf16.h>
#include <cstdint>
#include <cstddef>

// Problem constants (B=1)
#define EN 400000   // edges
#define NN 25000    // nodes
// D=128, H=4, DK=DV=32

typedef __attribute__((ext_vector_type(8))) short bf16x8;
typedef __attribute__((ext_vector_type(4))) short bf16x4;
typedef __attribute__((ext_vector_type(4))) float f32x4;

__device__ __forceinline__ short f2bf(float f) {
    unsigned int u = __float_as_uint(f);
    u = (u + 0x7fffu + ((u >> 16) & 1u)) >> 16;   // RNE
    return (short)u;
}
__device__ __forceinline__ float bf2f(short s) {
    return __uint_as_float(((unsigned int)(unsigned short)s) << 16);
}

// ---------------- K0: weights -> bf16 hi (5 mats) + bf16 lo (WQ,WK,WE) ----------------
__global__ __launch_bounds__(256) void convert_w_kernel(
    const float* __restrict__ w0, const float* __restrict__ w1,
    const float* __restrict__ w2, const float* __restrict__ w3,
    const float* __restrict__ w4, short* __restrict__ hi, short* __restrict__ lo)
{
    int i = blockIdx.x * 256 + threadIdx.x;      // 131072 threads total
    if (i < 81920) {
        int w = i >> 14, off = i & 16383;
        const float* src = (w == 0) ? w0 : (w == 1) ? w1 : (w == 2) ? w2 : (w == 3) ? w3 : w4;
        hi[i] = f2bf(src[off]);
    } else {
        int j = i - 81920;                       // 0..49151: WQ, WK, WE lo parts
        int m = j >> 14, off = j & 16383;
        const float* src = (m == 0) ? w0 : (m == 1) ? w1 : w3;
        float x = src[off];
        short h = f2bf(x);
        lo[j] = f2bf(x - bf2f(h));
    }
}

// ---------------- CSR build ----------------
__global__ __launch_bounds__(256) void hist_kernel(
    const int* __restrict__ eidx, int* __restrict__ deg)
{
    int e = blockIdx.x * 256 + threadIdx.x;
    if (e < EN) atomicAdd(&deg[eidx[e]], 1);
}

__global__ __launch_bounds__(1024) void scan_kernel(
    const int* __restrict__ deg, int* __restrict__ base)
{
    __shared__ int part[1024];
    const int t = threadIdx.x;
    const int CH = 25;                       // 1024*25 = 25600 >= NN
    int loc[CH];
    int s = 0;
#pragma unroll
    for (int i = 0; i < CH; ++i) {
        int idx = t * CH + i;
        loc[i] = s;
        s += (idx < NN) ? deg[idx] : 0;
    }
    part[t] = s;
    __syncthreads();
    for (int d = 1; d < 1024; d <<= 1) {
        int v = (t >= d) ? part[t - d] : 0;
        __syncthreads();
        part[t] += v;
        __syncthreads();
    }
    int off = (t > 0) ? part[t - 1] : 0;
#pragma unroll
    for (int i = 0; i < CH; ++i) {
        int idx = t * CH + i;
        if (idx < NN) base[idx] = off + loc[i];
    }
    if (t == 1023) base[NN] = part[1023];
}

// writes inv (edge -> csr pos) and tgt_csr (csr pos -> tgt node)
__global__ __launch_bounds__(256) void scatter_kernel(
    const int* __restrict__ eidx, const int* __restrict__ base,
    int* __restrict__ cnt, int* __restrict__ inv, int* __restrict__ tgt_csr)
{
    int e = blockIdx.x * 256 + threadIdx.x;
    if (e < EN) {
        int s = eidx[e];
        int p = base[s] + atomicAdd(&cnt[s], 1);
        inv[e] = p;
        tgt_csr[p] = eidx[EN + e];
    }
}

// ---------------- K1a: split-precision projection, fp32 output (Q, K) ----------------
__global__ __launch_bounds__(256) void proj_split_kernel(
    const float* __restrict__ X, const short* __restrict__ Whi,
    const short* __restrict__ Wlo, float* __restrict__ P, int nrows)
{
    const int lane = threadIdx.x & 63;
    const int wave = threadIdx.x >> 6;
    const int el = lane & 15;
    const int g  = lane >> 4;
    const int row = blockIdx.x * 64 + wave * 16 + el;
    const int rc  = row < nrows ? row : nrows - 1;

    f32x4 acc[8] = {};
    const float* xrow = X + (size_t)rc * 128;
#pragma unroll
    for (int kc = 0; kc < 4; ++kc) {
        const int kb = kc * 32 + g * 8;
        f32x4 x0 = *(const f32x4*)(xrow + kb);
        f32x4 x1 = *(const f32x4*)(xrow + kb + 4);
        bf16x8 bh, bl;
#pragma unroll
        for (int j = 0; j < 4; ++j) {
            bh[j] = f2bf(x0[j]); bl[j] = f2bf(x0[j] - bf2f(bh[j]));
            bh[4 + j] = f2bf(x1[j]); bl[4 + j] = f2bf(x1[j] - bf2f(bh[4 + j]));
        }
#pragma unroll
        for (int dt = 0; dt < 8; ++dt) {
            bf16x8 ah = *(const bf16x8*)(Whi + (dt * 16 + el) * 128 + kb);
            bf16x8 al = *(const bf16x8*)(Wlo + (dt * 16 + el) * 128 + kb);
            acc[dt] = __builtin_amdgcn_mfma_f32_16x16x32_bf16(ah, bh, acc[dt], 0, 0, 0);
            acc[dt] = __builtin_amdgcn_mfma_f32_16x16x32_bf16(ah, bl, acc[dt], 0, 0, 0);
            acc[dt] = __builtin_amdgcn_mfma_f32_16x16x32_bf16(al, bh, acc[dt], 0, 0, 0);
        }
    }
    if (row < nrows) {
#pragma unroll
        for (int dt = 0; dt < 8; ++dt)
            *(f32x4*)(P + (size_t)row * 128 + dt * 16 + g * 4) = acc[dt];
    }
}

// ---------------- K1b: single-pass bf16 projection (V) ----------------
__global__ __launch_bounds__(256) void proj_kernel(
    const float* __restrict__ X, const short* __restrict__ Wb,
    short* __restrict__ P, int nrows)
{
    const int lane = threadIdx.x & 63;
    const int wave = threadIdx.x >> 6;
    const int el = lane & 15;
    const int g  = lane >> 4;
    const int row = blockIdx.x * 64 + wave * 16 + el;
    const int rc  = row < nrows ? row : nrows - 1;

    f32x4 acc[8] = {};
    const float* xrow = X + (size_t)rc * 128;
#pragma unroll
    for (int kc = 0; kc < 4; ++kc) {
        const int kb = kc * 32 + g * 8;
        f32x4 x0 = *(const f32x4*)(xrow + kb);
        f32x4 x1 = *(const f32x4*)(xrow + kb + 4);
        bf16x8 b;
        b[0] = f2bf(x0[0]); b[1] = f2bf(x0[1]); b[2] = f2bf(x0[2]); b[3] = f2bf(x0[3]);
        b[4] = f2bf(x1[0]); b[5] = f2bf(x1[1]); b[6] = f2bf(x1[2]); b[7] = f2bf(x1[3]);
#pragma unroll
        for (int dt = 0; dt < 8; ++dt) {
            bf16x8 a = *(const bf16x8*)(Wb + (dt * 16 + el) * 128 + kb);
            acc[dt] = __builtin_amdgcn_mfma_f32_16x16x32_bf16(a, b, acc[dt], 0, 0, 0);
        }
    }
    if (row < nrows) {
#pragma unroll
        for (int dt = 0; dt < 8; ++dt) {
            bf16x4 o;
#pragma unroll
            for (int j = 0; j < 4; ++j) o[j] = f2bf(acc[dt][j]);
            *(bf16x4*)(P + (size_t)row * 128 + dt * 16 + g * 4) = o;
        }
    }
}

// ---------------- K2a: natural-order Ef-GEMM + score + exp (no V, no atomics) ---------
// Per wave: 16 consecutive edges. Lane owns edge e=lane&15, dims d = dt*16+g*4+j.
__global__ __launch_bounds__(256) void edge_score_kernel(
    const int* __restrict__ eidx, const int* __restrict__ inv,
    const float* __restrict__ efeat,
    const float* __restrict__ Qf, const float* __restrict__ Kf,
    const short* __restrict__ WEhi, const short* __restrict__ WElo,
    float* __restrict__ attn_out, float* __restrict__ attn_csr)
{
    const int lane = threadIdx.x & 63;
    const int wave = threadIdx.x >> 6;
    const int el = lane & 15;
    const int g  = lane >> 4;
    const int edge = blockIdx.x * 64 + wave * 16 + el;   // 6250*64 = 400000 exactly

    f32x4 acc[8] = {};
    const float* efrow = efeat + (size_t)edge * 128;
#pragma unroll
    for (int kc = 0; kc < 4; ++kc) {
        const int kb = kc * 32 + g * 8;
        f32x4 x0 = *(const f32x4*)(efrow + kb);
        f32x4 x1 = *(const f32x4*)(efrow + kb + 4);
        bf16x8 bh, bl;
#pragma unroll
        for (int j = 0; j < 4; ++j) {
            bh[j] = f2bf(x0[j]); bl[j] = f2bf(x0[j] - bf2f(bh[j]));
            bh[4 + j] = f2bf(x1[j]); bl[4 + j] = f2bf(x1[j] - bf2f(bh[4 + j]));
        }
#pragma unroll
        for (int dt = 0; dt < 8; ++dt) {
            bf16x8 ah = *(const bf16x8*)(WEhi + (dt * 16 + el) * 128 + kb);
            bf16x8 al = *(const bf16x8*)(WElo + (dt * 16 + el) * 128 + kb);
            acc[dt] = __builtin_amdgcn_mfma_f32_16x16x32_bf16(ah, bh, acc[dt], 0, 0, 0);
            acc[dt] = __builtin_amdgcn_mfma_f32_16x16x32_bf16(ah, bl, acc[dt], 0, 0, 0);
            acc[dt] = __builtin_amdgcn_mfma_f32_16x16x32_bf16(al, bh, acc[dt], 0, 0, 0);
        }
    }

    const int src = eidx[edge];
    const int tgt = eidx[EN + edge];
    const size_t qoff = (size_t)src * 128;
    const size_t koff = (size_t)tgt * 128;

    float part[4] = {0.f, 0.f, 0.f, 0.f};
#pragma unroll
    for (int dt = 0; dt < 8; ++dt) {
        const int dbase = dt * 16 + g * 4;
        f32x4 q4 = *(const f32x4*)(Qf + qoff + dbase);
        f32x4 k4 = *(const f32x4*)(Kf + koff + dbase);
        const int h = dt >> 1;
#pragma unroll
        for (int j = 0; j < 4; ++j)
            part[h] += q4[j] * k4[j] * acc[dt][j];
    }

    float attn[4];
#pragma unroll
    for (int h = 0; h < 4; ++h) {
        float t = part[h];
        t += __shfl_xor(t, 16, 64);
        t += __shfl_xor(t, 32, 64);           // all 4 g-lanes now hold full 32-sum
        t *= 0.17677669529663687f;            // 1/sqrt(32)
        t = fminf(5.0f, fmaxf(-5.0f, t));
        attn[h] = expf(t);
    }

    attn_out[(size_t)g * EN + edge] = attn[g];         // coalesced per 16-lane group
    const int p = inv[edge];
    attn_csr[(size_t)p * 4 + g] = attn[g];             // scattered 16B per edge (4 lanes)
}

// ---------------- K2b: per-node gather-reduce + W_fc matvec + residual + LN ----------
// Block: 256 threads = 16 nodes. Group of 16 lanes owns one node; lane el covers
// dims el*8..el*8+7 (head el>>2) in the gather phase, dims c16+16*i in the matvec.
__global__ __launch_bounds__(256) void node_kernel(
    const int* __restrict__ base, const int* __restrict__ tgt_csr,
    const float* __restrict__ attn_csr, const short* __restrict__ Vb,
    const short* __restrict__ Wfcb, const float* __restrict__ inQ,
    const float* __restrict__ gamma, const float* __restrict__ beta,
    float* __restrict__ y)
{
    __shared__ short wlds[128 * 136];   // padded: stride 136 bf16 -> 2-way banks
    __shared__ float alds[16 * 132];    // padded: stride 132 f32

    const int t = threadIdx.x;
    // stage W_fc (bf16): thread handles row r=t>>1, cols (t&1)*64..+63
    {
        const int r = t >> 1, colb = (t & 1) * 64;
#pragma unroll
        for (int c = 0; c < 8; ++c) {
            bf16x8 w = *(const bf16x8*)(Wfcb + r * 128 + colb + c * 8);
            *(bf16x8*)(&wlds[r * 136 + colb + c * 8]) = w;
        }
    }

    const int n_l = t >> 4;
    const int el  = t & 15;
    const int node = blockIdx.x * 16 + n_l;

    // gather-reduce this node's edges (contiguous CSR slice)
    int b0 = 0, b1 = 0;
    if (node < NN) { b0 = base[node]; b1 = base[node + 1]; }
    float acc[8] = {};
    float csum = 0.f;
    const int h = el >> 2;
    for (int p = b0; p < b1; ++p) {
        const int tgt = tgt_csr[p];
        const float a = attn_csr[(size_t)p * 4 + h];
        bf16x8 v = *(const bf16x8*)(Vb + (size_t)tgt * 128 + el * 8);
        csum += a;
#pragma unroll
        for (int j = 0; j < 8; ++j) acc[j] += a * bf2f(v[j]);
    }
    const float invc = 1.0f / (csum + 1e-8f);
#pragma unroll
    for (int j = 0; j < 8; ++j) alds[n_l * 132 + el * 8 + j] = acc[j] * invc;
    __syncthreads();

    // W_fc matvec from LDS
    float fc[8] = {};
#pragma unroll 4
    for (int k0 = 0; k0 < 128; k0 += 8) {
        float a8[8];
#pragma unroll
        for (int j = 0; j < 8; ++j) a8[j] = alds[n_l * 132 + k0 + j];
#pragma unroll
        for (int i = 0; i < 8; ++i) {
            const int d = el + 16 * i;
            bf16x8 w = *(const bf16x8*)(&wlds[d * 136 + k0]);
#pragma unroll
            for (int j = 0; j < 8; ++j) fc[i] += a8[j] * bf2f(w[j]);
        }
    }

    if (node < NN) {
        float x[8];
        float s = 0.f, s2 = 0.f;
#pragma unroll
        for (int i = 0; i < 8; ++i) {
            const int d = el + 16 * i;
            x[i] = fc[i] + inQ[(size_t)node * 128 + d];
            s += x[i]; s2 += x[i] * x[i];
        }
        // reduce across the 16 threads of this node (lanes differ in low 4 bits)
        s  += __shfl_xor(s, 1, 64);  s2 += __shfl_xor(s2, 1, 64);
        s  += __shfl_xor(s, 2, 64);  s2 += __shfl_xor(s2, 2, 64);
        s  += __shfl_xor(s, 4, 64);  s2 += __shfl_xor(s2, 4, 64);
        s  += __shfl_xor(s, 8, 64);  s2 += __shfl_xor(s2, 8, 64);
        const float mu = s * (1.0f / 128.0f);
        const float var = s2 * (1.0f / 128.0f) - mu * mu;
        const float rstd = rsqrtf(var + 1e-5f);
#pragma unroll
        for (int i = 0; i < 8; ++i) {
            const int d = el + 16 * i;
            y[(size_t)node * 128 + d] = (x[i] - mu) * rstd * gamma[d] + beta[d];
        }
    }
}

// ---------------- launcher ----------------
extern "C" void kernel_launch(void* const* d_in, const int* in_sizes, int n_in,
                              void* d_out, int out_size, void* d_ws, size_t ws_size,
                              hipStream_t stream) {
    const int*   eidx  = (const int*)d_in[0];
    const float* efeat = (const float*)d_in[1];
    const float* inQ   = (const float*)d_in[2];
    const float* inK   = (const float*)d_in[3];
    const float* inV   = (const float*)d_in[4];
    const float* WQ    = (const float*)d_in[5];
    const float* WK    = (const float*)d_in[6];
    const float* WV    = (const float*)d_in[7];
    const float* WE    = (const float*)d_in[8];
    const float* Wfc   = (const float*)d_in[9];
    const float* gamma = (const float*)d_in[10];
    const float* beta  = (const float*)d_in[11];

    float* y = (float*)d_out;
    float* attn_out = y + (size_t)NN * 128;   // 3,200,000

    // ws layout (bytes):
    //   Qf f32:            12,800,000 @ 0
    //   Kf f32:            12,800,000 @ 12,800,000
    //   Vb bf16:            6,400,000 @ 25,600,000
    //   Whi (5x16384):        163,840 @ 32,000,000
    //   Wlo (3x16384):         98,304 @ 32,163,840
    //   attn_csr f32:       6,400,000 @ 32,262,144
    //   tgt_csr int:        1,600,000 @ 38,662,144
    //   inv int:            1,600,000 @ 40,262,144
    //   deg int:              100,352 @ 41,862,144
    //   cnt int:              100,352 @ 41,962,496
    //   base int (NN+1):      100,352 @ 42,062,848  -> total 42,163,200
    char* ws = (char*)d_ws;
    float* Qf      = (float*)ws;
    float* Kf      = (float*)(ws + 12800000);
    short* Vb      = (short*)(ws + 25600000);
    short* Whi     = (short*)(ws + 32000000);
    short* Wlo     = (short*)(ws + 32163840);
    float* attn_csr= (float*)(ws + 32262144);
    int*   tgt_csr = (int*)  (ws + 38662144);
    int*   inv     = (int*)  (ws + 40262144);
    int*   deg     = (int*)  (ws + 41862144);
    int*   cnt     = (int*)  (ws + 41962496);
    int*   base    = (int*)  (ws + 42062848);

    hipMemsetAsync(deg, 0, 200704, stream);   // deg + cnt

    // CSR build
    hist_kernel<<<(EN + 255) / 256, 256, 0, stream>>>(eidx, deg);
    scan_kernel<<<1, 1024, 0, stream>>>(deg, base);
    scatter_kernel<<<(EN + 255) / 256, 256, 0, stream>>>(eidx, base, cnt, inv, tgt_csr);

    convert_w_kernel<<<512, 256, 0, stream>>>(WQ, WK, WV, WE, Wfc, Whi, Wlo);

    proj_split_kernel<<<391, 256, 0, stream>>>(inQ, Whi,         Wlo,         Qf, NN);
    proj_split_kernel<<<391, 256, 0, stream>>>(inK, Whi + 16384, Wlo + 16384, Kf, NN);
    proj_kernel<<<391, 256, 0, stream>>>(inV, Whi + 2 * 16384, Vb, NN);

    edge_score_kernel<<<EN / 64, 256, 0, stream>>>(eidx, inv, efeat, Qf, Kf,
                                                   Whi + 3 * 16384, Wlo + 2 * 16384,
                                                   attn_out, attn_csr);

    node_kernel<<<(NN + 15) / 16, 256, 0, stream>>>(base, tgt_csr, attn_csr, Vb,
                                                    Whi + 4 * 16384, inQ, gamma, beta, y);
}

// Round 5
// 338.579 us; speedup vs baseline: 2.5767x; 1.3133x over previous
//
#include <hip/hip_runtime.h>
#include <hip/hip_bf16.h>
#include <cstdint>
#include <cstddef>

// Problem constants (B=1)
#define EN 400000   // edges
#define NN 25000    // nodes
// D=128, H=4, DK=DV=32

typedef __attribute__((ext_vector_type(8))) short bf16x8;
typedef __attribute__((ext_vector_type(4))) short bf16x4;
typedef __attribute__((ext_vector_type(4))) float f32x4;

__device__ __forceinline__ short f2bf(float f) {
    unsigned int u = __float_as_uint(f);
    u = (u + 0x7fffu + ((u >> 16) & 1u)) >> 16;   // RNE
    return (short)u;
}
__device__ __forceinline__ float bf2f(short s) {
    return __uint_as_float(((unsigned int)(unsigned short)s) << 16);
}

// ---------------- K0: weights -> bf16 hi (5 mats) + bf16 lo (WQ,WK,WE) ----------------
__global__ __launch_bounds__(256) void convert_w_kernel(
    const float* __restrict__ w0, const float* __restrict__ w1,
    const float* __restrict__ w2, const float* __restrict__ w3,
    const float* __restrict__ w4, short* __restrict__ hi, short* __restrict__ lo)
{
    int i = blockIdx.x * 256 + threadIdx.x;      // 131072 threads total
    if (i < 81920) {
        int w = i >> 14, off = i & 16383;
        const float* src = (w == 0) ? w0 : (w == 1) ? w1 : (w == 2) ? w2 : (w == 3) ? w3 : w4;
        hi[i] = f2bf(src[off]);
    } else {
        int j = i - 81920;                       // 0..49151: WQ, WK, WE lo parts
        int m = j >> 14, off = j & 16383;
        const float* src = (m == 0) ? w0 : (m == 1) ? w1 : w3;
        float x = src[off];
        short h = f2bf(x);
        lo[j] = f2bf(x - bf2f(h));
    }
}

// ---------------- CSR build ----------------
__global__ __launch_bounds__(256) void hist_kernel(
    const int* __restrict__ eidx, int* __restrict__ deg)
{
    int e = blockIdx.x * 256 + threadIdx.x;
    if (e < EN) atomicAdd(&deg[eidx[e]], 1);
}

__global__ __launch_bounds__(1024) void scan_kernel(
    const int* __restrict__ deg, int* __restrict__ base)
{
    __shared__ int part[1024];
    const int t = threadIdx.x;
    const int CH = 25;                       // 1024*25 = 25600 >= NN
    int loc[CH];
    int s = 0;
#pragma unroll
    for (int i = 0; i < CH; ++i) {
        int idx = t * CH + i;
        loc[i] = s;
        s += (idx < NN) ? deg[idx] : 0;
    }
    part[t] = s;
    __syncthreads();
    for (int d = 1; d < 1024; d <<= 1) {
        int v = (t >= d) ? part[t - d] : 0;
        __syncthreads();
        part[t] += v;
        __syncthreads();
    }
    int off = (t > 0) ? part[t - 1] : 0;
#pragma unroll
    for (int i = 0; i < CH; ++i) {
        int idx = t * CH + i;
        if (idx < NN) base[idx] = off + loc[i];
    }
    if (t == 1023) base[NN] = part[1023];
}

// writes inv (edge -> csr pos) and tgt_csr (csr pos -> tgt node)
__global__ __launch_bounds__(256) void scatter_kernel(
    const int* __restrict__ eidx, const int* __restrict__ base,
    int* __restrict__ cnt, int* __restrict__ inv, int* __restrict__ tgt_csr)
{
    int e = blockIdx.x * 256 + threadIdx.x;
    if (e < EN) {
        int s = eidx[e];
        int p = base[s] + atomicAdd(&cnt[s], 1);
        inv[e] = p;
        tgt_csr[p] = eidx[EN + e];
    }
}

// ---------------- K1a: head-split split-precision projection, fp32 out (Q, K) --------
// Wave hw = head hw: outdims [32hw, 32hw+32). Weight frags VGPR-resident.
__global__ __launch_bounds__(256, 4) void proj_split_kernel(
    const float* __restrict__ X, const short* __restrict__ Whi,
    const short* __restrict__ Wlo, float* __restrict__ P, int nrows)
{
    const int lane = threadIdx.x & 63;
    const int hw = threadIdx.x >> 6;          // head / wave
    const int el = lane & 15;
    const int g  = lane >> 4;

    bf16x8 wh[2][4], wl[2][4];
#pragma unroll
    for (int dtt = 0; dtt < 2; ++dtt)
#pragma unroll
        for (int kc = 0; kc < 4; ++kc) {
            const int r = hw * 32 + dtt * 16 + el;
            const int c = kc * 32 + g * 8;
            wh[dtt][kc] = *(const bf16x8*)(Whi + r * 128 + c);
            wl[dtt][kc] = *(const bf16x8*)(Wlo + r * 128 + c);
        }

    const int ntiles = (nrows + 15) >> 4;
    for (int tile = blockIdx.x; tile < ntiles; tile += gridDim.x) {
        const int row = tile * 16 + el;
        const int rc = row < nrows ? row : nrows - 1;
        const float* xrow = X + (size_t)rc * 128;
        f32x4 acc0 = {}, acc1 = {};
#pragma unroll
        for (int kc = 0; kc < 4; ++kc) {
            const int kb = kc * 32 + g * 8;
            f32x4 x0 = *(const f32x4*)(xrow + kb);
            f32x4 x1 = *(const f32x4*)(xrow + kb + 4);
            bf16x8 bh, bl;
#pragma unroll
            for (int j = 0; j < 4; ++j) {
                bh[j] = f2bf(x0[j]); bl[j] = f2bf(x0[j] - bf2f(bh[j]));
                bh[4 + j] = f2bf(x1[j]); bl[4 + j] = f2bf(x1[j] - bf2f(bh[4 + j]));
            }
            acc0 = __builtin_amdgcn_mfma_f32_16x16x32_bf16(wh[0][kc], bh, acc0, 0, 0, 0);
            acc0 = __builtin_amdgcn_mfma_f32_16x16x32_bf16(wh[0][kc], bl, acc0, 0, 0, 0);
            acc0 = __builtin_amdgcn_mfma_f32_16x16x32_bf16(wl[0][kc], bh, acc0, 0, 0, 0);
            acc1 = __builtin_amdgcn_mfma_f32_16x16x32_bf16(wh[1][kc], bh, acc1, 0, 0, 0);
            acc1 = __builtin_amdgcn_mfma_f32_16x16x32_bf16(wh[1][kc], bl, acc1, 0, 0, 0);
            acc1 = __builtin_amdgcn_mfma_f32_16x16x32_bf16(wl[1][kc], bh, acc1, 0, 0, 0);
        }
        if (row < nrows) {
            *(f32x4*)(P + (size_t)row * 128 + hw * 32 + g * 4)      = acc0;
            *(f32x4*)(P + (size_t)row * 128 + hw * 32 + 16 + g * 4) = acc1;
        }
    }
}

// ---------------- K1b: head-split single-pass bf16 projection (V) ----------------
__global__ __launch_bounds__(256, 4) void proj_kernel(
    const float* __restrict__ X, const short* __restrict__ Wb,
    short* __restrict__ P, int nrows)
{
    const int lane = threadIdx.x & 63;
    const int hw = threadIdx.x >> 6;
    const int el = lane & 15;
    const int g  = lane >> 4;

    bf16x8 wv[2][4];
#pragma unroll
    for (int dtt = 0; dtt < 2; ++dtt)
#pragma unroll
        for (int kc = 0; kc < 4; ++kc)
            wv[dtt][kc] = *(const bf16x8*)(Wb + (hw * 32 + dtt * 16 + el) * 128 + kc * 32 + g * 8);

    const int ntiles = (nrows + 15) >> 4;
    for (int tile = blockIdx.x; tile < ntiles; tile += gridDim.x) {
        const int row = tile * 16 + el;
        const int rc = row < nrows ? row : nrows - 1;
        const float* xrow = X + (size_t)rc * 128;
        f32x4 acc0 = {}, acc1 = {};
#pragma unroll
        for (int kc = 0; kc < 4; ++kc) {
            const int kb = kc * 32 + g * 8;
            f32x4 x0 = *(const f32x4*)(xrow + kb);
            f32x4 x1 = *(const f32x4*)(xrow + kb + 4);
            bf16x8 b;
#pragma unroll
            for (int j = 0; j < 4; ++j) { b[j] = f2bf(x0[j]); b[4 + j] = f2bf(x1[j]); }
            acc0 = __builtin_amdgcn_mfma_f32_16x16x32_bf16(wv[0][kc], b, acc0, 0, 0, 0);
            acc1 = __builtin_amdgcn_mfma_f32_16x16x32_bf16(wv[1][kc], b, acc1, 0, 0, 0);
        }
        if (row < nrows) {
            bf16x4 o0, o1;
#pragma unroll
            for (int j = 0; j < 4; ++j) { o0[j] = f2bf(acc0[j]); o1[j] = f2bf(acc1[j]); }
            *(bf16x4*)(P + (size_t)row * 128 + hw * 32 + g * 4)      = o0;
            *(bf16x4*)(P + (size_t)row * 128 + hw * 32 + 16 + g * 4) = o1;
        }
    }
}

// ---------------- K2a: head-split Ef-GEMM + score + exp (weights VGPR-resident) -------
// Wave hw = head hw. Per tile: 16 edges; lane (el,g) owns edge el, dims hw*32+dtt*16+g*4+j.
__global__ __launch_bounds__(256, 4) void edge_score_kernel(
    const int* __restrict__ eidx, const int* __restrict__ inv,
    const float* __restrict__ efeat,
    const float* __restrict__ Qf, const float* __restrict__ Kf,
    const short* __restrict__ WEhi, const short* __restrict__ WElo,
    float* __restrict__ attn_out, float* __restrict__ attn_csr)
{
    const int lane = threadIdx.x & 63;
    const int hw = threadIdx.x >> 6;          // head / wave
    const int el = lane & 15;
    const int g  = lane >> 4;

    bf16x8 wh[2][4], wl[2][4];
#pragma unroll
    for (int dtt = 0; dtt < 2; ++dtt)
#pragma unroll
        for (int kc = 0; kc < 4; ++kc) {
            const int r = hw * 32 + dtt * 16 + el;
            const int c = kc * 32 + g * 8;
            wh[dtt][kc] = *(const bf16x8*)(WEhi + r * 128 + c);
            wl[dtt][kc] = *(const bf16x8*)(WElo + r * 128 + c);
        }

    for (int tile = blockIdx.x; tile < EN / 16; tile += gridDim.x) {
        const int edge = tile * 16 + el;
        const float* efrow = efeat + (size_t)edge * 128;
        f32x4 acc0 = {}, acc1 = {};
#pragma unroll
        for (int kc = 0; kc < 4; ++kc) {
            const int kb = kc * 32 + g * 8;
            f32x4 x0 = *(const f32x4*)(efrow + kb);
            f32x4 x1 = *(const f32x4*)(efrow + kb + 4);
            bf16x8 bh, bl;
#pragma unroll
            for (int j = 0; j < 4; ++j) {
                bh[j] = f2bf(x0[j]); bl[j] = f2bf(x0[j] - bf2f(bh[j]));
                bh[4 + j] = f2bf(x1[j]); bl[4 + j] = f2bf(x1[j] - bf2f(bh[4 + j]));
            }
            acc0 = __builtin_amdgcn_mfma_f32_16x16x32_bf16(wh[0][kc], bh, acc0, 0, 0, 0);
            acc0 = __builtin_amdgcn_mfma_f32_16x16x32_bf16(wh[0][kc], bl, acc0, 0, 0, 0);
            acc0 = __builtin_amdgcn_mfma_f32_16x16x32_bf16(wl[0][kc], bh, acc0, 0, 0, 0);
            acc1 = __builtin_amdgcn_mfma_f32_16x16x32_bf16(wh[1][kc], bh, acc1, 0, 0, 0);
            acc1 = __builtin_amdgcn_mfma_f32_16x16x32_bf16(wh[1][kc], bl, acc1, 0, 0, 0);
            acc1 = __builtin_amdgcn_mfma_f32_16x16x32_bf16(wl[1][kc], bh, acc1, 0, 0, 0);
        }

        const int src = eidx[edge];
        const int tgt = eidx[EN + edge];
        const int dbase = hw * 32 + g * 4;
        f32x4 q0 = *(const f32x4*)(Qf + (size_t)src * 128 + dbase);
        f32x4 k0 = *(const f32x4*)(Kf + (size_t)tgt * 128 + dbase);
        f32x4 q1 = *(const f32x4*)(Qf + (size_t)src * 128 + dbase + 16);
        f32x4 k1 = *(const f32x4*)(Kf + (size_t)tgt * 128 + dbase + 16);

        float part = 0.f;
#pragma unroll
        for (int j = 0; j < 4; ++j) {
            part += q0[j] * k0[j] * acc0[j];
            part += q1[j] * k1[j] * acc1[j];
        }
        part += __shfl_xor(part, 16, 64);
        part += __shfl_xor(part, 32, 64);
        float t = part * 0.17677669529663687f;     // 1/sqrt(32)
        t = fminf(5.0f, fmaxf(-5.0f, t));
        const float a = __expf(t);

        if (g == 0) {
            attn_out[(size_t)hw * EN + edge] = a;              // coalesced 64B per wave
            attn_csr[(size_t)inv[edge] * 4 + hw] = a;          // scattered 4B
        }
    }
}

// ---------------- K2b: per-node gather-reduce + W_fc matvec + residual + LN ----------
// Block: 256 threads = 16 nodes. 16 lanes per node; lane el covers dims el*8..+7 in the
// gather (head el>>2), dims el+16*i in the matvec.
__global__ __launch_bounds__(256) void node_kernel(
    const int* __restrict__ base, const int* __restrict__ tgt_csr,
    const float* __restrict__ attn_csr, const short* __restrict__ Vb,
    const short* __restrict__ Wfcb, const float* __restrict__ inQ,
    const float* __restrict__ gamma, const float* __restrict__ beta,
    float* __restrict__ y)
{
    __shared__ short wlds[128 * 136];   // padded: stride 136 bf16 -> 2-way banks
    __shared__ float alds[16 * 132];    // padded: stride 132 f32

    const int t = threadIdx.x;
    {
        const int r = t >> 1, colb = (t & 1) * 64;
#pragma unroll
        for (int c = 0; c < 8; ++c) {
            bf16x8 w = *(const bf16x8*)(Wfcb + r * 128 + colb + c * 8);
            *(bf16x8*)(&wlds[r * 136 + colb + c * 8]) = w;
        }
    }

    const int n_l = t >> 4;
    const int el  = t & 15;
    const int node = blockIdx.x * 16 + n_l;

    int b0 = 0, b1 = 0;
    if (node < NN) { b0 = base[node]; b1 = base[node + 1]; }
    float acc[8] = {};
    float csum = 0.f;
    const int h = el >> 2;

    int p = b0;
    for (; p + 4 <= b1; p += 4) {      // unroll x4 for memory-level parallelism
        const int t0 = tgt_csr[p],     t1 = tgt_csr[p + 1];
        const int t2 = tgt_csr[p + 2], t3 = tgt_csr[p + 3];
        const float a0 = attn_csr[(size_t)p * 4 + h];
        const float a1 = attn_csr[(size_t)(p + 1) * 4 + h];
        const float a2 = attn_csr[(size_t)(p + 2) * 4 + h];
        const float a3 = attn_csr[(size_t)(p + 3) * 4 + h];
        bf16x8 v0 = *(const bf16x8*)(Vb + (size_t)t0 * 128 + el * 8);
        bf16x8 v1 = *(const bf16x8*)(Vb + (size_t)t1 * 128 + el * 8);
        bf16x8 v2 = *(const bf16x8*)(Vb + (size_t)t2 * 128 + el * 8);
        bf16x8 v3 = *(const bf16x8*)(Vb + (size_t)t3 * 128 + el * 8);
        csum += (a0 + a1) + (a2 + a3);
#pragma unroll
        for (int j = 0; j < 8; ++j) {
            acc[j] += a0 * bf2f(v0[j]) + a1 * bf2f(v1[j])
                    + a2 * bf2f(v2[j]) + a3 * bf2f(v3[j]);
        }
    }
    for (; p < b1; ++p) {
        const int tg = tgt_csr[p];
        const float a = attn_csr[(size_t)p * 4 + h];
        bf16x8 v = *(const bf16x8*)(Vb + (size_t)tg * 128 + el * 8);
        csum += a;
#pragma unroll
        for (int j = 0; j < 8; ++j) acc[j] += a * bf2f(v[j]);
    }

    const float invc = 1.0f / (csum + 1e-8f);
#pragma unroll
    for (int j = 0; j < 8; ++j) alds[n_l * 132 + el * 8 + j] = acc[j] * invc;
    __syncthreads();

    float fc[8] = {};
#pragma unroll 4
    for (int k0 = 0; k0 < 128; k0 += 8) {
        float a8[8];
#pragma unroll
        for (int j = 0; j < 8; ++j) a8[j] = alds[n_l * 132 + k0 + j];
#pragma unroll
        for (int i = 0; i < 8; ++i) {
            const int d = el + 16 * i;
            bf16x8 w = *(const bf16x8*)(&wlds[d * 136 + k0]);
#pragma unroll
            for (int j = 0; j < 8; ++j) fc[i] += a8[j] * bf2f(w[j]);
        }
    }

    if (node < NN) {
        float x[8];
        float s = 0.f, s2 = 0.f;
#pragma unroll
        for (int i = 0; i < 8; ++i) {
            const int d = el + 16 * i;
            x[i] = fc[i] + inQ[(size_t)node * 128 + d];
            s += x[i]; s2 += x[i] * x[i];
        }
        s  += __shfl_xor(s, 1, 64);  s2 += __shfl_xor(s2, 1, 64);
        s  += __shfl_xor(s, 2, 64);  s2 += __shfl_xor(s2, 2, 64);
        s  += __shfl_xor(s, 4, 64);  s2 += __shfl_xor(s2, 4, 64);
        s  += __shfl_xor(s, 8, 64);  s2 += __shfl_xor(s2, 8, 64);
        const float mu = s * (1.0f / 128.0f);
        const float var = s2 * (1.0f / 128.0f) - mu * mu;
        const float rstd = rsqrtf(var + 1e-5f);
#pragma unroll
        for (int i = 0; i < 8; ++i) {
            const int d = el + 16 * i;
            y[(size_t)node * 128 + d] = (x[i] - mu) * rstd * gamma[d] + beta[d];
        }
    }
}

// ---------------- launcher ----------------
extern "C" void kernel_launch(void* const* d_in, const int* in_sizes, int n_in,
                              void* d_out, int out_size, void* d_ws, size_t ws_size,
                              hipStream_t stream) {
    const int*   eidx  = (const int*)d_in[0];
    const float* efeat = (const float*)d_in[1];
    const float* inQ   = (const float*)d_in[2];
    const float* inK   = (const float*)d_in[3];
    const float* inV   = (const float*)d_in[4];
    const float* WQ    = (const float*)d_in[5];
    const float* WK    = (const float*)d_in[6];
    const float* WV    = (const float*)d_in[7];
    const float* WE    = (const float*)d_in[8];
    const float* Wfc   = (const float*)d_in[9];
    const float* gamma = (const float*)d_in[10];
    const float* beta  = (const float*)d_in[11];

    float* y = (float*)d_out;
    float* attn_out = y + (size_t)NN * 128;   // 3,200,000

    // ws layout (bytes): same as R4
    char* ws = (char*)d_ws;
    float* Qf      = (float*)ws;
    float* Kf      = (float*)(ws + 12800000);
    short* Vb      = (short*)(ws + 25600000);
    short* Whi     = (short*)(ws + 32000000);
    short* Wlo     = (short*)(ws + 32163840);
    float* attn_csr= (float*)(ws + 32262144);
    int*   tgt_csr = (int*)  (ws + 38662144);
    int*   inv     = (int*)  (ws + 40262144);
    int*   deg     = (int*)  (ws + 41862144);
    int*   cnt     = (int*)  (ws + 41962496);
    int*   base    = (int*)  (ws + 42062848);

    hipMemsetAsync(deg, 0, 200704, stream);   // deg + cnt

    // CSR build
    hist_kernel<<<(EN + 255) / 256, 256, 0, stream>>>(eidx, deg);
    scan_kernel<<<1, 1024, 0, stream>>>(deg, base);
    scatter_kernel<<<(EN + 255) / 256, 256, 0, stream>>>(eidx, base, cnt, inv, tgt_csr);

    convert_w_kernel<<<512, 256, 0, stream>>>(WQ, WK, WV, WE, Wfc, Whi, Wlo);

    proj_split_kernel<<<1563, 256, 0, stream>>>(inQ, Whi,         Wlo,         Qf, NN);
    proj_split_kernel<<<1563, 256, 0, stream>>>(inK, Whi + 16384, Wlo + 16384, Kf, NN);
    proj_kernel<<<1563, 256, 0, stream>>>(inV, Whi + 2 * 16384, Vb, NN);

    edge_score_kernel<<<2048, 256, 0, stream>>>(eidx, inv, efeat, Qf, Kf,
                                                Whi + 3 * 16384, Wlo + 2 * 16384,
                                                attn_out, attn_csr);

    node_kernel<<<(NN + 15) / 16, 256, 0, stream>>>(base, tgt_csr, attn_csr, Vb,
                                                    Whi + 4 * 16384, inQ, gamma, beta, y);
}